// Round 1
// baseline (1122.634 us; speedup 1.0000x reference)
//
#include <hip/hip_runtime.h>
#include <hip/hip_bf16.h>

#define EPSBN 1e-5f
#define NEG_SLOPE 0.2f

// ---- workspace layout (float offsets) ----
// region A is reused: y1 lives until pac2 consumes it, then y3/y4/g3 move in.
#define O_Y1      0            // 128*59*59*32 = 14,258,176
#define O_Y3      0            // 128*14*14*128 = 3,211,264 (after y1 dead)
#define O_Y4      3211264      // 128*6*6*256 = 1,179,648
#define O_G3      4390912      // 128*14*14 = 25,088
#define O_G1      14258176     // 128*59*59 = 445,568
#define O_Y2      14703744     // 128*29*29*64 = 6,889,472
#define O_G2      21593216     // 128*29*29 = 107,648
#define O_WK2     21700864     // 9*32*64  = 18,432
#define O_WK3     21719296     // 9*64*128 = 73,728
#define O_WK4     21793024     // 9*128*256 = 294,912
#define O_W1R     22087936     // 9*32 = 288
#define O_WADVR   22088224     // 9216
#define O_STATS   22097440     // (64+128+256)*2 = 896  (s,t per channel)
#define O_PART    22098336     // 131,072 partial sums
// total = 22,229,408 floats = 88.9 MB

// Repack all weights once per call:
//  wk[l] layout [k][ci][co]  (co fastest -> coalesced lane reads)
//  wadv repacked to NHWC flatten order, pre-scaled by 1/sqrt(9216)
__global__ void repack_kernel(const float* __restrict__ w1,
                              const float* __restrict__ w2,
                              const float* __restrict__ w3,
                              const float* __restrict__ w4,
                              const float* __restrict__ wadv,
                              float* __restrict__ ws) {
  int idx = blockIdx.x * 256 + threadIdx.x;
  if (idx < 18432) {                       // wk2: co=64, ci=32
    int co = idx & 63; int t = idx >> 6; int ci = t & 31; int k = t >> 5;
    ws[O_WK2 + idx] = w2[(co * 32 + ci) * 9 + k];
  } else if (idx < 92160) {                // wk3: co=128, ci=64
    int i = idx - 18432;
    int co = i & 127; int t = i >> 7; int ci = t & 63; int k = t >> 6;
    ws[O_WK3 + i] = w3[(co * 64 + ci) * 9 + k];
  } else if (idx < 387072) {               // wk4: co=256, ci=128
    int i = idx - 92160;
    int co = i & 255; int t = i >> 8; int ci = t & 127; int k = t >> 7;
    ws[O_WK4 + i] = w4[(co * 128 + ci) * 9 + k];
  } else if (idx < 387360) {               // w1r: [k][co], co=32
    int i = idx - 387072;
    int co = i & 31; int k = i >> 5;
    ws[O_W1R + i] = w1[co * 9 + k];
  } else if (idx < 396576) {               // wadv -> NHWC order, prescaled
    int i = idx - 387360;
    int c = i & 255; int hw = i >> 8;      // i = hw*256 + c ; src = c*36 + hw
    ws[O_WADVR + i] = wadv[c * 36 + hw] * (1.0f / 96.0f);
  }
}

// conv1 (Cin=1) + leaky relu. Output NHWC (N,59,59,32); idx layout == output layout.
__global__ void conv1_kernel(const float* __restrict__ x,
                             const float* __restrict__ w1r,
                             const float* __restrict__ b1,
                             float* __restrict__ y1) {
  int idx = blockIdx.x * 256 + threadIdx.x;   // total 14,258,176 (exact grid)
  int co = idx & 31;
  int t = idx >> 5;
  int ow = t % 59; t /= 59;
  int oh = t % 59; int n = t / 59;
  const float* xb = x + (n * 120 + oh * 2) * 120 + ow * 2;
  float acc = b1[co];
#pragma unroll
  for (int kh = 0; kh < 3; ++kh)
#pragma unroll
    for (int kw = 0; kw < 3; ++kw)
      acc += xb[kh * 120 + kw] * w1r[(kh * 3 + kw) * 32 + co];
  y1[idx] = acc >= 0.0f ? acc : NEG_SLOPE * acc;
}

// 3x3/2 avg pool on (N,H,H) guide
__global__ void avgpool_kernel(const float* __restrict__ gin, float* __restrict__ gout,
                               int HI, int HO, int total) {
  int idx = blockIdx.x * 256 + threadIdx.x;
  if (idx >= total) return;
  int ow = idx % HO; int t = idx / HO; int oh = t % HO; int n = t / HO;
  const float* gb = gin + (n * HI + oh * 2) * HI + ow * 2;
  float s = 0.0f;
#pragma unroll
  for (int kh = 0; kh < 3; ++kh)
#pragma unroll
    for (int kw = 0; kw < 3; ++kw)
      s += gb[kh * HI + kw];
  gout[idx] = s * (1.0f / 9.0f);
}

// PacConv + leaky relu. x: NHWC (N,HI,HI,CI); g: (N,HI,HI); wk: [k][ci][co]; y: NHWC (N,HO,HO,CO).
// Each thread computes 4 batch images (same co,oh,ow) -> 4x weight-load amortization.
template <int CI, int CO, int HI, int HO>
__global__ void pac_kernel(const float* __restrict__ x, const float* __restrict__ g,
                           const float* __restrict__ wk, const float* __restrict__ b,
                           float* __restrict__ y) {
  int idx = blockIdx.x * 256 + threadIdx.x;   // total CO*HO*HO*(N/4), exact grid
  int co = idx % CO; int t = idx / CO;
  int ow = t % HO; t /= HO;
  int oh = t % HO; int nb = t / HO;
  int n0 = nb * 4;

  // gaussian kernels per (m, tap)
  float kker[4][9];
#pragma unroll
  for (int m = 0; m < 4; ++m) {
    const float* gb = g + ((n0 + m) * HI + oh * 2) * HI + ow * 2;
    float gc = gb[HI + 1];
#pragma unroll
    for (int kh = 0; kh < 3; ++kh)
#pragma unroll
      for (int kw = 0; kw < 3; ++kw) {
        float d = gb[kh * HI + kw] - gc;
        kker[m][kh * 3 + kw] = __expf(-0.5f * d * d);
      }
  }

  float acc[4];
#pragma unroll
  for (int m = 0; m < 4; ++m) acc[m] = b[co];

  for (int kh = 0; kh < 3; ++kh) {
    for (int kw = 0; kw < 3; ++kw) {
      int k = kh * 3 + kw;
      int ih = oh * 2 + kh, iw = ow * 2 + kw;
      const float* wb = wk + k * CI * CO + co;
      float pk[4] = {0.0f, 0.0f, 0.0f, 0.0f};
#pragma unroll 4
      for (int c4 = 0; c4 < CI / 4; ++c4) {
        float w0 = wb[(c4 * 4 + 0) * CO];
        float w1v = wb[(c4 * 4 + 1) * CO];
        float w2v = wb[(c4 * 4 + 2) * CO];
        float w3v = wb[(c4 * 4 + 3) * CO];
#pragma unroll
        for (int m = 0; m < 4; ++m) {
          const float4 xv = *reinterpret_cast<const float4*>(
              x + (((n0 + m) * HI + ih) * HI + iw) * CI + c4 * 4);
          pk[m] += xv.x * w0 + xv.y * w1v + xv.z * w2v + xv.w * w3v;
        }
      }
#pragma unroll
      for (int m = 0; m < 4; ++m) acc[m] += pk[m] * kker[m][k];
    }
  }
#pragma unroll
  for (int m = 0; m < 4; ++m) {
    float v = acc[m];
    v = v >= 0.0f ? v : NEG_SLOPE * v;
    y[(((n0 + m) * HO + oh) * HO + ow) * CO + co] = v;
  }
}

// deterministic BN stats, stage 1: 65536 threads, fixed channel per thread, fixed slots
template <int C>
__global__ void bnstat1_kernel(const float* __restrict__ y, float* __restrict__ part, int total) {
  int t = threadIdx.x;
  int gidx = blockIdx.x * 256 + t;            // grid fixed at 256 blocks
  float s = 0.0f, q = 0.0f;
  for (int e = gidx; e < total; e += 65536) {
    float v = y[e];
    s += v; q += v * v;
  }
  int c = t & (C - 1);
  int slot = blockIdx.x * (256 / C) + t / C;  // nslots = 65536/C
  constexpr int NS = 65536 / C;
  part[(c * NS + slot) * 2 + 0] = s;
  part[(c * NS + slot) * 2 + 1] = q;
}

// stage 2: one block per channel, tree reduce, emit (scale, shift)
template <int C>
__global__ void bnstat2_kernel(const float* __restrict__ part,
                               const float* __restrict__ gamma,
                               const float* __restrict__ beta,
                               float* __restrict__ st, float invM) {
  constexpr int NS = 65536 / C;
  int c = blockIdx.x;
  int t = threadIdx.x;
  float s = 0.0f, q = 0.0f;
  for (int slot = t; slot < NS; slot += 256) {
    s += part[(c * NS + slot) * 2 + 0];
    q += part[(c * NS + slot) * 2 + 1];
  }
  __shared__ float ss[256], sq[256];
  ss[t] = s; sq[t] = q; __syncthreads();
  for (int off = 128; off > 0; off >>= 1) {
    if (t < off) { ss[t] += ss[t + off]; sq[t] += sq[t + off]; }
    __syncthreads();
  }
  if (t == 0) {
    float m = ss[0] * invM;
    float v = sq[0] * invM - m * m;
    float sc = gamma[c] * rsqrtf(v + EPSBN);
    st[2 * c] = sc;
    st[2 * c + 1] = beta[c] - m * sc;
  }
}

template <int C>
__global__ void bnapply_kernel(float* __restrict__ y, const float* __restrict__ st, int total) {
  int idx = blockIdx.x * 256 + threadIdx.x;   // exact grids used
  int c = idx & (C - 1);
  y[idx] = y[idx] * st[2 * c] + st[2 * c + 1];
}

// final EqualLinear: one block per batch image
__global__ void linear_kernel(const float* __restrict__ y4, const float* __restrict__ wadvr,
                              const float* __restrict__ badv, float* __restrict__ out) {
  int n = blockIdx.x, t = threadIdx.x;
  float s = 0.0f;
  for (int j = t; j < 9216; j += 256) s += y4[n * 9216 + j] * wadvr[j];
  __shared__ float ss[256];
  ss[t] = s; __syncthreads();
  for (int off = 128; off > 0; off >>= 1) {
    if (t < off) ss[t] += ss[t + off];
    __syncthreads();
  }
  if (t == 0) out[n] = ss[0] + badv[0];
}

extern "C" void kernel_launch(void* const* d_in, const int* in_sizes, int n_in,
                              void* d_out, int out_size, void* d_ws, size_t ws_size,
                              hipStream_t stream) {
  const float* x    = (const float*)d_in[0];
  const float* gd   = (const float*)d_in[1];
  const float* w1   = (const float*)d_in[2];
  const float* b1   = (const float*)d_in[3];
  const float* w2   = (const float*)d_in[4];
  const float* b2   = (const float*)d_in[5];
  const float* w3   = (const float*)d_in[6];
  const float* b3   = (const float*)d_in[7];
  const float* w4   = (const float*)d_in[8];
  const float* b4   = (const float*)d_in[9];
  const float* bg2  = (const float*)d_in[10];
  const float* bb2  = (const float*)d_in[11];
  const float* bg3  = (const float*)d_in[12];
  const float* bb3  = (const float*)d_in[13];
  const float* bg4  = (const float*)d_in[14];
  const float* bb4  = (const float*)d_in[15];
  const float* wadv = (const float*)d_in[16];
  const float* badv = (const float*)d_in[17];
  float* out = (float*)d_out;
  float* ws  = (float*)d_ws;

  repack_kernel<<<1550, 256, 0, stream>>>(w1, w2, w3, w4, wadv, ws);
  conv1_kernel<<<55696, 256, 0, stream>>>(x, ws + O_W1R, b1, ws + O_Y1);
  avgpool_kernel<<<1741, 256, 0, stream>>>(gd, ws + O_G1, 120, 59, 445568);

  pac_kernel<32, 64, 59, 29><<<6728, 256, 0, stream>>>(ws + O_Y1, ws + O_G1, ws + O_WK2, b2, ws + O_Y2);
  bnstat1_kernel<64><<<256, 256, 0, stream>>>(ws + O_Y2, ws + O_PART, 6889472);
  bnstat2_kernel<64><<<64, 256, 0, stream>>>(ws + O_PART, bg2, bb2, ws + O_STATS, 1.0f / 107648.0f);
  bnapply_kernel<64><<<26912, 256, 0, stream>>>(ws + O_Y2, ws + O_STATS, 6889472);
  avgpool_kernel<<<421, 256, 0, stream>>>(ws + O_G1, ws + O_G2, 59, 29, 107648);

  pac_kernel<64, 128, 29, 14><<<3136, 256, 0, stream>>>(ws + O_Y2, ws + O_G2, ws + O_WK3, b3, ws + O_Y3);
  bnstat1_kernel<128><<<256, 256, 0, stream>>>(ws + O_Y3, ws + O_PART, 3211264);
  bnstat2_kernel<128><<<128, 256, 0, stream>>>(ws + O_PART, bg3, bb3, ws + O_STATS + 128, 1.0f / 25088.0f);
  bnapply_kernel<128><<<12544, 256, 0, stream>>>(ws + O_Y3, ws + O_STATS + 128, 3211264);
  avgpool_kernel<<<98, 256, 0, stream>>>(ws + O_G2, ws + O_G3, 29, 14, 25088);

  pac_kernel<128, 256, 14, 6><<<1152, 256, 0, stream>>>(ws + O_Y3, ws + O_G3, ws + O_WK4, b4, ws + O_Y4);
  bnstat1_kernel<256><<<256, 256, 0, stream>>>(ws + O_Y4, ws + O_PART, 1179648);
  bnstat2_kernel<256><<<256, 256, 0, stream>>>(ws + O_PART, bg4, bb4, ws + O_STATS + 384, 1.0f / 4608.0f);
  bnapply_kernel<256><<<4608, 256, 0, stream>>>(ws + O_Y4, ws + O_STATS + 384, 1179648);

  linear_kernel<<<128, 256, 0, stream>>>(ws + O_Y4, ws + O_WADVR, badv, out);
}

// Round 2
// 872.301 us; speedup vs baseline: 1.2870x; 1.2870x over previous
//
#include <hip/hip_runtime.h>
#include <hip/hip_bf16.h>

#define EPSBN 1e-5f
#define NEG_SLOPE 0.2f

// ---- workspace layout (float offsets) ----
#define O_Y1      0            // 128*59*59*32 = 14,258,176
#define O_Y3      0            // 128*14*14*128 = 3,211,264 (after y1 dead)
#define O_Y4      3211264      // 128*6*6*256 = 1,179,648
#define O_G3      4390912      // 128*14*14 = 25,088
#define O_G1      14258176     // 128*59*59 = 445,568
#define O_Y2      14703744     // 128*29*29*64 = 6,889,472
#define O_G2      21593216     // 128*29*29 = 107,648
#define O_WK2     21700864     // 9*32*64  = 18,432
#define O_WK3     21719296     // 9*64*128 = 73,728
#define O_WK4     21793024     // 9*128*256 = 294,912
#define O_W1R     22087936     // 9*32 = 288
#define O_WADVR   22088224     // 9216
#define O_STATS   22097440     // st2[128] st3[256] st4[512] = 896  ([sc[C]; sh[C]])
#define O_PART    22098336     // max 64*421*2 = 53,888
// total < 22.16M floats = 88.7 MB (same footprint as round 1)

__global__ void repack_kernel(const float* __restrict__ w1,
                              const float* __restrict__ w2,
                              const float* __restrict__ w3,
                              const float* __restrict__ w4,
                              const float* __restrict__ wadv,
                              float* __restrict__ ws) {
  int idx = blockIdx.x * 256 + threadIdx.x;
  if (idx < 18432) {                       // wk2 [k][ci][co]: co=64, ci=32
    int co = idx & 63; int t = idx >> 6; int ci = t & 31; int k = t >> 5;
    ws[O_WK2 + idx] = w2[(co * 32 + ci) * 9 + k];
  } else if (idx < 92160) {                // wk3: co=128, ci=64
    int i = idx - 18432;
    int co = i & 127; int t = i >> 7; int ci = t & 63; int k = t >> 6;
    ws[O_WK3 + i] = w3[(co * 64 + ci) * 9 + k];
  } else if (idx < 387072) {               // wk4: co=256, ci=128
    int i = idx - 92160;
    int co = i & 255; int t = i >> 8; int ci = t & 127; int k = t >> 7;
    ws[O_WK4 + i] = w4[(co * 128 + ci) * 9 + k];
  } else if (idx < 387360) {               // w1r: [k][co], co=32
    int i = idx - 387072;
    int co = i & 31; int k = i >> 5;
    ws[O_W1R + i] = w1[co * 9 + k];
  } else if (idx < 396576) {               // wadv -> NHWC flatten order, prescaled
    int i = idx - 387360;
    int c = i & 255; int hw = i >> 8;      // i = hw*256 + c ; src = c*36 + hw
    ws[O_WADVR + i] = wadv[c * 36 + hw] * (1.0f / 96.0f);
  }
}

// conv1 (Cin=1) + leaky relu -> NHWC (N,59,59,32)
__global__ void conv1_kernel(const float* __restrict__ x,
                             const float* __restrict__ w1r,
                             const float* __restrict__ b1,
                             float* __restrict__ y1) {
  int idx = blockIdx.x * 256 + threadIdx.x;   // exact grid 14,258,176
  int co = idx & 31;
  int t = idx >> 5;
  int ow = t % 59; t /= 59;
  int oh = t % 59; int n = t / 59;
  const float* xb = x + (n * 120 + oh * 2) * 120 + ow * 2;
  float acc = b1[co];
#pragma unroll
  for (int kh = 0; kh < 3; ++kh)
#pragma unroll
    for (int kw = 0; kw < 3; ++kw)
      acc += xb[kh * 120 + kw] * w1r[(kh * 3 + kw) * 32 + co];
  y1[idx] = acc >= 0.0f ? acc : NEG_SLOPE * acc;
}

__global__ void avgpool_kernel(const float* __restrict__ gin, float* __restrict__ gout,
                               int HI, int HO, int total) {
  int idx = blockIdx.x * 256 + threadIdx.x;
  if (idx >= total) return;
  int ow = idx % HO; int t = idx / HO; int oh = t % HO; int n = t / HO;
  const float* gb = gin + (n * HI + oh * 2) * HI + ow * 2;
  float s = 0.0f;
#pragma unroll
  for (int kh = 0; kh < 3; ++kh)
#pragma unroll
    for (int kw = 0; kw < 3; ++kw)
      s += gb[kh * HI + kw];
  gout[idx] = s * (1.0f / 9.0f);
}

// PacConv + lrelu + fused input-BN + fused output BN partial stats.
// lanes = pixels, co register-blocked (CO_BLK accs/thread); weight loads are
// block-uniform broadcasts (L1/K$-served). x NHWC, wk [k][ci][co], y NHWC (pre-BN, lrelu'd).
// part[co][NBLK][2] per-block partial (sum, sumsq), deterministic fixed slots.
template <int CI, int CO, int CO_BLK, int HI, int HO, bool BN_IN, int PIX, int NBLK>
__global__ void pac_kernel(const float* __restrict__ x, const float* __restrict__ g,
                           const float* __restrict__ wk, const float* __restrict__ b,
                           const float* __restrict__ bnsc, const float* __restrict__ bnsh,
                           float* __restrict__ y, float* __restrict__ part) {
  const int tid = threadIdx.x;
  const int blk = blockIdx.x % NBLK;
  const int bcot = blockIdx.x / NBLK;
  const int co0 = bcot * CO_BLK;
  const int p = blk * 256 + tid;
  const bool valid = p < PIX;
  const int pc = valid ? p : 0;

  int ow = pc % HO; int t = pc / HO; int oh = t % HO; int n = t / (HO);
  n = pc / (HO * HO);
  oh = (pc / HO) % HO;

  const float* gb = g + (n * HI + oh * 2) * HI + ow * 2;
  const float gc = gb[HI + 1];

  float acc[CO_BLK];
#pragma unroll
  for (int cg = 0; cg < CO_BLK / 4; ++cg) {
    float4 bv = *reinterpret_cast<const float4*>(b + co0 + cg * 4);
    acc[cg * 4 + 0] = bv.x; acc[cg * 4 + 1] = bv.y;
    acc[cg * 4 + 2] = bv.z; acc[cg * 4 + 3] = bv.w;
  }

  const float* xbase = x + n * (HI * HI * CI);

#pragma unroll 1
  for (int kh = 0; kh < 3; ++kh) {
#pragma unroll 1
    for (int kw = 0; kw < 3; ++kw) {
      const int k = kh * 3 + kw;
      float d = gb[kh * HI + kw] - gc;
      float kk = __expf(-0.5f * d * d);
      const float* xr = xbase + ((oh * 2 + kh) * HI + (ow * 2 + kw)) * CI;
      const float* wr = wk + k * (CI * CO) + co0;
#pragma unroll 4
      for (int c4 = 0; c4 < CI / 4; ++c4) {
        float4 xv = *reinterpret_cast<const float4*>(xr + c4 * 4);
        if (BN_IN) {
          float4 sc = *reinterpret_cast<const float4*>(bnsc + c4 * 4);
          float4 sh = *reinterpret_cast<const float4*>(bnsh + c4 * 4);
          xv.x = xv.x * sc.x + sh.x; xv.y = xv.y * sc.y + sh.y;
          xv.z = xv.z * sc.z + sh.z; xv.w = xv.w * sc.w + sh.w;
        }
        float xa0 = xv.x * kk, xa1 = xv.y * kk, xa2 = xv.z * kk, xa3 = xv.w * kk;
        const float* wc = wr + (c4 * 4) * CO;
#pragma unroll
        for (int cg = 0; cg < CO_BLK / 4; ++cg) {
          float4 w0 = *reinterpret_cast<const float4*>(wc + 0 * CO + cg * 4);
          acc[cg * 4 + 0] += xa0 * w0.x; acc[cg * 4 + 1] += xa0 * w0.y;
          acc[cg * 4 + 2] += xa0 * w0.z; acc[cg * 4 + 3] += xa0 * w0.w;
        }
#pragma unroll
        for (int cg = 0; cg < CO_BLK / 4; ++cg) {
          float4 w1v = *reinterpret_cast<const float4*>(wc + 1 * CO + cg * 4);
          acc[cg * 4 + 0] += xa1 * w1v.x; acc[cg * 4 + 1] += xa1 * w1v.y;
          acc[cg * 4 + 2] += xa1 * w1v.z; acc[cg * 4 + 3] += xa1 * w1v.w;
        }
#pragma unroll
        for (int cg = 0; cg < CO_BLK / 4; ++cg) {
          float4 w2v = *reinterpret_cast<const float4*>(wc + 2 * CO + cg * 4);
          acc[cg * 4 + 0] += xa2 * w2v.x; acc[cg * 4 + 1] += xa2 * w2v.y;
          acc[cg * 4 + 2] += xa2 * w2v.z; acc[cg * 4 + 3] += xa2 * w2v.w;
        }
#pragma unroll
        for (int cg = 0; cg < CO_BLK / 4; ++cg) {
          float4 w3v = *reinterpret_cast<const float4*>(wc + 3 * CO + cg * 4);
          acc[cg * 4 + 0] += xa3 * w3v.x; acc[cg * 4 + 1] += xa3 * w3v.y;
          acc[cg * 4 + 2] += xa3 * w3v.z; acc[cg * 4 + 3] += xa3 * w3v.w;
        }
      }
    }
  }

  // epilogue: lrelu, store, per-channel partial (sum, sumsq)
  __shared__ float ps[4][2 * CO_BLK];
  const int wv = tid >> 6;
  const int lane = tid & 63;
#pragma unroll
  for (int cg = 0; cg < CO_BLK / 4; ++cg) {
    float o[4];
#pragma unroll
    for (int j = 0; j < 4; ++j) {
      float v = acc[cg * 4 + j];
      o[j] = v >= 0.0f ? v : NEG_SLOPE * v;
    }
    if (valid) {
      float4 o4; o4.x = o[0]; o4.y = o[1]; o4.z = o[2]; o4.w = o[3];
      *reinterpret_cast<float4*>(y + (size_t)p * CO + co0 + cg * 4) = o4;
    }
#pragma unroll
    for (int j = 0; j < 4; ++j) {
      float s = valid ? o[j] : 0.0f;
      float q = s * s;
#pragma unroll
      for (int off = 1; off < 64; off <<= 1) {
        s += __shfl_xor(s, off, 64);
        q += __shfl_xor(q, off, 64);
      }
      if (lane == 0) {
        ps[wv][(cg * 4 + j) * 2 + 0] = s;
        ps[wv][(cg * 4 + j) * 2 + 1] = q;
      }
    }
  }
  __syncthreads();
  if (tid < CO_BLK) {
    float s = ps[0][tid * 2] + ps[1][tid * 2] + ps[2][tid * 2] + ps[3][tid * 2];
    float q = ps[0][tid * 2 + 1] + ps[1][tid * 2 + 1] + ps[2][tid * 2 + 1] + ps[3][tid * 2 + 1];
    part[((co0 + tid) * NBLK + blk) * 2 + 0] = s;
    part[((co0 + tid) * NBLK + blk) * 2 + 1] = q;
  }
}

// reduce partials -> st = [sc[C]; sh[C]]
template <int C>
__global__ void bnstat2_kernel(const float* __restrict__ part,
                               const float* __restrict__ gamma,
                               const float* __restrict__ beta,
                               float* __restrict__ st, float invM, int NBLK) {
  int c = blockIdx.x;
  int t = threadIdx.x;
  float s = 0.0f, q = 0.0f;
  for (int slot = t; slot < NBLK; slot += 256) {
    s += part[(c * NBLK + slot) * 2 + 0];
    q += part[(c * NBLK + slot) * 2 + 1];
  }
  __shared__ float ss[256], sq[256];
  ss[t] = s; sq[t] = q; __syncthreads();
  for (int off = 128; off > 0; off >>= 1) {
    if (t < off) { ss[t] += ss[t + off]; sq[t] += sq[t + off]; }
    __syncthreads();
  }
  if (t == 0) {
    float m = ss[0] * invM;
    float v = sq[0] * invM - m * m;
    float sc = gamma[c] * rsqrtf(v + EPSBN);
    st[c] = sc;
    st[C + c] = beta[c] - m * sc;
  }
}

// EqualLinear with fused BN4 on input
__global__ void linear_kernel(const float* __restrict__ y4, const float* __restrict__ st4,
                              const float* __restrict__ wadvr, const float* __restrict__ badv,
                              float* __restrict__ out) {
  int n = blockIdx.x, t = threadIdx.x;
  float sc = st4[t], sh = st4[256 + t];  // c = j & 255 == t for stride-256 loop
  float s = 0.0f;
  for (int j = t; j < 9216; j += 256) s += (y4[n * 9216 + j] * sc + sh) * wadvr[j];
  __shared__ float ss[256];
  ss[t] = s; __syncthreads();
  for (int off = 128; off > 0; off >>= 1) {
    if (t < off) ss[t] += ss[t + off];
    __syncthreads();
  }
  if (t == 0) out[n] = ss[0] + badv[0];
}

extern "C" void kernel_launch(void* const* d_in, const int* in_sizes, int n_in,
                              void* d_out, int out_size, void* d_ws, size_t ws_size,
                              hipStream_t stream) {
  const float* x    = (const float*)d_in[0];
  const float* gd   = (const float*)d_in[1];
  const float* w1   = (const float*)d_in[2];
  const float* b1   = (const float*)d_in[3];
  const float* w2   = (const float*)d_in[4];
  const float* b2   = (const float*)d_in[5];
  const float* w3   = (const float*)d_in[6];
  const float* b3   = (const float*)d_in[7];
  const float* w4   = (const float*)d_in[8];
  const float* b4   = (const float*)d_in[9];
  const float* bg2  = (const float*)d_in[10];
  const float* bb2  = (const float*)d_in[11];
  const float* bg3  = (const float*)d_in[12];
  const float* bb3  = (const float*)d_in[13];
  const float* bg4  = (const float*)d_in[14];
  const float* bb4  = (const float*)d_in[15];
  const float* wadv = (const float*)d_in[16];
  const float* badv = (const float*)d_in[17];
  float* out = (float*)d_out;
  float* ws  = (float*)d_ws;

  float* st2 = ws + O_STATS;        // [sc64; sh64]
  float* st3 = ws + O_STATS + 128;  // [sc128; sh128]
  float* st4 = ws + O_STATS + 384;  // [sc256; sh256]

  repack_kernel<<<1550, 256, 0, stream>>>(w1, w2, w3, w4, wadv, ws);
  conv1_kernel<<<55696, 256, 0, stream>>>(x, ws + O_W1R, b1, ws + O_Y1);
  avgpool_kernel<<<1741, 256, 0, stream>>>(gd, ws + O_G1, 120, 59, 445568);

  // pac2: CI=32 CO=64 CO_BLK=32: 2 cotiles x 421 blocks
  pac_kernel<32, 64, 32, 59, 29, false, 107648, 421><<<842, 256, 0, stream>>>(
      ws + O_Y1, ws + O_G1, ws + O_WK2, b2, nullptr, nullptr, ws + O_Y2, ws + O_PART);
  bnstat2_kernel<64><<<64, 256, 0, stream>>>(ws + O_PART, bg2, bb2, st2, 1.0f / 107648.0f, 421);
  avgpool_kernel<<<421, 256, 0, stream>>>(ws + O_G1, ws + O_G2, 59, 29, 107648);

  // pac3: CI=64 CO=128 CO_BLK=32: 4 cotiles x 98 blocks
  pac_kernel<64, 128, 32, 29, 14, true, 25088, 98><<<392, 256, 0, stream>>>(
      ws + O_Y2, ws + O_G2, ws + O_WK3, b3, st2, st2 + 64, ws + O_Y3, ws + O_PART);
  bnstat2_kernel<128><<<128, 256, 0, stream>>>(ws + O_PART, bg3, bb3, st3, 1.0f / 25088.0f, 98);
  avgpool_kernel<<<98, 256, 0, stream>>>(ws + O_G2, ws + O_G3, 29, 14, 25088);

  // pac4: CI=128 CO=256 CO_BLK=32: 8 cotiles x 18 blocks
  pac_kernel<128, 256, 32, 14, 6, true, 4608, 18><<<144, 256, 0, stream>>>(
      ws + O_Y3, ws + O_G3, ws + O_WK4, b4, st3, st3 + 128, ws + O_Y4, ws + O_PART);
  bnstat2_kernel<256><<<256, 256, 0, stream>>>(ws + O_PART, bg4, bb4, st4, 1.0f / 4608.0f, 18);

  linear_kernel<<<128, 256, 0, stream>>>(ws + O_Y4, st4, ws + O_WADVR, badv, out);
}